// Round 1
// 116.946 us; speedup vs baseline: 1.0058x; 1.0058x over previous
//
#include <hip/hip_runtime.h>
#include <hip/hip_bf16.h>

// flex_conv via MFMA + pipelined async LDS staging (v2).
//
// Math (unchanged, validated): t[k=ic*4+d][pixel]: t_d = ctr_d*Xs - PX_d (d<3),
// t_3 = Xs; out[o][pixel] = Kmat[o][k] . t[k][pixel] -> 16x16x32 bf16 MFMA
// (A[m=p][k], B[k][n=p], D row=c*4+r col=p).
//
// v2 structure: block = 256 thr (4 waves) owns a 64-col strip and FOUR
// consecutive 4-row output tiles (16 output rows). Input rows are staged in
// ALIGNED groups of 4 rows x 19 planes x 68 cols (20672 B) into a 3-slot
// rolling LDS buffer via async global_load_lds (width 16, no VGPR
// round-trip).  Group g -> slot g%3.  Tile u reads groups g0+u, g0+u+1;
// group g0+u+2 is prefetched asynchronously DURING compute of tile u, so
// HBM latency hides under VALU/LDS work (m97 pattern).  Stores for tile u
// are issued at the top of iteration u+1 so their completion also hides
// under compute.  LDS layout [row][plane][chunk] makes the lane->LDS map
// exactly base + lane*16 (global_load_lds requirement: wave-uniform base).
// Halo staging drops 6/4 -> 5/4 rows; blocks 2048 -> 512 (2/CU by LDS).

#define HH 64
#define WW 512
#define HP 62
#define WP 510
#define IC 16
#define OC 32
#define BS 16
#define RB 4                   // output rows per tile
#define TC 64                  // output cols per block
#define LCW 68                 // floats per plane-row in LDS (need 66)
#define CPR 17                 // float4 chunks per plane-row (17*4 = 68)
#define NPL 19                 // planes staged: 16 x + 3 pts
#define RPF (NPL * LCW)        // 1292: row stride (floats) within a group
#define GRPF (4 * RPF)         // 5168 floats = 20672 B per 4-row group
#define NGC (4 * NPL * CPR)    // 1292 float4 chunks per group
#define NSLOT 3                // rolling buffer slots
#define NTILE 4                // tiles per block (16 output rows)

typedef __attribute__((ext_vector_type(8))) short short8;
typedef __attribute__((ext_vector_type(4))) float f32x4;

static __device__ __forceinline__ short f2bf(float f) {
    union { __hip_bfloat16 h; short s; } u;
    u.h = __float2bfloat16(f);
    return u.s;
}

// Async-stage one aligned 4-row group (rows 4g..4g+3) into slot g%3.
// cid = tid + rnd*256 maps to LDS byte offset cid*16 from the slot base,
// so each wave's 64 lanes write base + lane*16 (contiguous) as required.
static __device__ __forceinline__ void stage_group(
    const float* __restrict__ xb, const float* __restrict__ pb,
    float* lds, int g, int j0, int tid)
{
    float* slotbase = lds + (g % NSLOT) * GRPF;
    #pragma unroll
    for (int rnd = 0; rnd < 6; ++rnd) {
        const int cid = tid + rnd * 256;
        if (cid < NGC) {
            const int r = cid / (NPL * CPR);           // 0..3 row in group
            const int rem = cid - r * (NPL * CPR);
            const int plane = rem / CPR;               // 0..18
            const int chunk = rem - plane * CPR;       // 0..16
            const float* base = (plane < IC)
                ? (xb + (size_t)plane * HH * WW)
                : (pb + (size_t)(plane - IC) * HH * WW);
            int gcol = j0 + chunk * 4;
            if (gcol > WW - 4) gcol = WW - 4;          // clamp (garbage unused)
            const float* src = base + (size_t)(g * 4 + r) * WW + gcol;
            __builtin_amdgcn_global_load_lds(
                (const __attribute__((address_space(1))) void*)src,
                (__attribute__((address_space(3))) void*)(slotbase + cid * 4),
                16, 0, 0);
        }
    }
}

__global__ __launch_bounds__(256) void flex_conv_pipe(
    const float* __restrict__ x, const float* __restrict__ kern,
    const float* __restrict__ pts, float* __restrict__ out)
{
    __shared__ float lds[NSLOT * GRPF];   // 15504 floats = 62016 B

    const int tid = threadIdx.x;
    const int j0 = blockIdx.x * TC;
    const int ch = blockIdx.y;            // row-chunk: output rows 16ch..16ch+15
    const int b = blockIdx.z;

    const float* xb = x + (size_t)b * IC * HH * WW;
    const float* pb = pts + (size_t)b * 3 * HH * WW;

    const int g0 = 4 * ch;
    const int gend = (ch == 3) ? 15 : (g0 + 4);

    // ---- async prologue staging of the first two groups ----
    stage_group(xb, pb, lds, g0, j0, tid);
    stage_group(xb, pb, lds, g0 + 1, j0, tid);

    // ---- A fragments (overlaps the DMA above) ----
    const int lane = tid & 63;
    const int wave = tid >> 6;
    const int p = lane & 15;
    const int c = lane >> 4;
    const int tc = wave * 16 + p;        // tile col of this lane's pixel

    short8 a0lo, a0hi, a1lo, a1hi;
    {
        const float4* k0v = (const float4*)(kern + (size_t)p * 64 + c * 8);
        const float4* k1v = (const float4*)(kern + (size_t)(16 + p) * 64 + c * 8);
        float4 v0a = k0v[0], v0b = k0v[1], v0c = k0v[8], v0d = k0v[9];
        float4 v1a = k1v[0], v1b = k1v[1], v1c = k1v[8], v1d = k1v[9];
        a0lo[0]=f2bf(v0a.x); a0lo[1]=f2bf(v0a.y); a0lo[2]=f2bf(v0a.z); a0lo[3]=f2bf(v0a.w);
        a0lo[4]=f2bf(v0b.x); a0lo[5]=f2bf(v0b.y); a0lo[6]=f2bf(v0b.z); a0lo[7]=f2bf(v0b.w);
        a0hi[0]=f2bf(v0c.x); a0hi[1]=f2bf(v0c.y); a0hi[2]=f2bf(v0c.z); a0hi[3]=f2bf(v0c.w);
        a0hi[4]=f2bf(v0d.x); a0hi[5]=f2bf(v0d.y); a0hi[6]=f2bf(v0d.z); a0hi[7]=f2bf(v0d.w);
        a1lo[0]=f2bf(v1a.x); a1lo[1]=f2bf(v1a.y); a1lo[2]=f2bf(v1a.z); a1lo[3]=f2bf(v1a.w);
        a1lo[4]=f2bf(v1b.x); a1lo[5]=f2bf(v1b.y); a1lo[6]=f2bf(v1b.z); a1lo[7]=f2bf(v1b.w);
        a1hi[0]=f2bf(v1c.x); a1hi[1]=f2bf(v1c.y); a1hi[2]=f2bf(v1c.z); a1hi[3]=f2bf(v1c.w);
        a1hi[4]=f2bf(v1d.x); a1hi[5]=f2bf(v1d.y); a1hi[6]=f2bf(v1d.z); a1hi[7]=f2bf(v1d.w);
    }

    __syncthreads();   // drains prologue DMA (vmcnt(0)) + barrier

    const int j = j0 + tc;
    float* const ob0 = out + (size_t)b * OC * HP * WP + j;

    f32x4 sa0[RB], sa1[RB];   // pending stores (tile u stored in iter u+1)
    int pi0 = 0;

    for (int u = 0; u < NTILE; ++u) {
        // ---- async prefetch of group needed by tile u+1 ----
        const int gpre = g0 + 2 + u;
        if (gpre <= gend) stage_group(xb, pb, lds, gpre, j0, tid);

        // ---- deferred store of previous tile (overlaps compute below) ----
        if (u > 0 && j < WP) {
            #pragma unroll
            for (int q = 0; q < RB; ++q) {
                float* ob = ob0 + (size_t)(pi0 + q) * WP;
                #pragma unroll
                for (int r = 0; r < 4; ++r) {
                    const int o = c * 4 + r;
                    ob[(size_t)o * HP * WP]        = sa0[q][r];
                    ob[(size_t)(o + 16) * HP * WP] = sa1[q][r];
                }
            }
        }

        int i0 = 16 * ch + RB * u;
        if (i0 > HP - RB) i0 = HP - RB;   // tail overlap (benign identical rewrite)

        // ---- window partials from LDS (groups g0+u, g0+u+1: already drained) ----
        float xs[4][RB], px0[4][RB], px1[4][RB], px2[4][RB];
        #pragma unroll
        for (int t = 0; t < 4; ++t)
            #pragma unroll
            for (int q = 0; q < RB; ++q) { xs[t][q]=0.f; px0[t][q]=0.f; px1[t][q]=0.f; px2[t][q]=0.f; }
        float c0[RB], c1[RB], c2[RB];

        #pragma unroll
        for (int rr = 0; rr < RB + 2; ++rr) {
            const int ir = i0 + rr;
            const int sb = ((ir >> 2) % NSLOT) * GRPF + (ir & 3) * RPF + tc;
            const float* lp0 = &lds[sb + (IC + 0) * LCW];
            const float* lp1 = &lds[sb + (IC + 1) * LCW];
            const float* lp2 = &lds[sb + (IC + 2) * LCW];
            const float pa0 = lp0[0], pm0 = lp0[1], pz0 = lp0[2];
            const float pa1 = lp1[0], pm1 = lp1[1], pz1 = lp1[2];
            const float pa2 = lp2[0], pm2 = lp2[1], pz2 = lp2[2];
            if (rr >= 1 && rr <= RB) { c0[rr-1] = pm0; c1[rr-1] = pm1; c2[rr-1] = pm2; }
            #pragma unroll
            for (int t = 0; t < 4; ++t) {
                const int icp = (t >> 1) * 8 + 2 * c + (t & 1);
                const float* lx = &lds[sb + icp * LCW];
                const float x0 = lx[0], x1 = lx[1], x2 = lx[2];
                const float rsx = x0 + x1 + x2;
                float r0 = pa0 * x0; r0 = fmaf(pm0, x1, r0); r0 = fmaf(pz0, x2, r0);
                float r1 = pa1 * x0; r1 = fmaf(pm1, x1, r1); r1 = fmaf(pz1, x2, r1);
                float r2 = pa2 * x0; r2 = fmaf(pm2, x1, r2); r2 = fmaf(pz2, x2, r2);
                #pragma unroll
                for (int q = 0; q < RB; ++q) {
                    if (rr >= q && rr <= q + 2) {
                        xs[t][q] += rsx; px0[t][q] += r0; px1[t][q] += r1; px2[t][q] += r2;
                    }
                }
            }
        }

        // ---- B fragments -> MFMA; keep accs for deferred store ----
        #pragma unroll
        for (int q = 0; q < RB; ++q) {
            short8 blo, bhi;
            #pragma unroll
            for (int t = 0; t < 4; ++t) {
                const short t0 = f2bf(fmaf(c0[q], xs[t][q], -px0[t][q]));
                const short t1 = f2bf(fmaf(c1[q], xs[t][q], -px1[t][q]));
                const short t2 = f2bf(fmaf(c2[q], xs[t][q], -px2[t][q]));
                const short t3 = f2bf(xs[t][q]);
                const int s = (t & 1) * 4;
                if (t < 2) { blo[s+0]=t0; blo[s+1]=t1; blo[s+2]=t2; blo[s+3]=t3; }
                else       { bhi[s+0]=t0; bhi[s+1]=t1; bhi[s+2]=t2; bhi[s+3]=t3; }
            }
            f32x4 acc0 = {0.f,0.f,0.f,0.f}, acc1 = {0.f,0.f,0.f,0.f};
            acc0 = __builtin_amdgcn_mfma_f32_16x16x32_bf16(a0lo, blo, acc0, 0, 0, 0);
            acc0 = __builtin_amdgcn_mfma_f32_16x16x32_bf16(a0hi, bhi, acc0, 0, 0, 0);
            acc1 = __builtin_amdgcn_mfma_f32_16x16x32_bf16(a1lo, blo, acc1, 0, 0, 0);
            acc1 = __builtin_amdgcn_mfma_f32_16x16x32_bf16(a1hi, bhi, acc1, 0, 0, 0);
            sa0[q] = acc0; sa1[q] = acc1;
        }
        pi0 = i0;

        // barrier drains this iter's prefetch DMA (+ deferred stores); skip on last
        if (u + 1 < NTILE) __syncthreads();
    }

    // ---- final tile store ----
    if (j < WP) {
        #pragma unroll
        for (int q = 0; q < RB; ++q) {
            float* ob = ob0 + (size_t)(pi0 + q) * WP;
            #pragma unroll
            for (int r = 0; r < 4; ++r) {
                const int o = c * 4 + r;
                ob[(size_t)o * HP * WP]        = sa0[q][r];
                ob[(size_t)(o + 16) * HP * WP] = sa1[q][r];
            }
        }
    }
}

extern "C" void kernel_launch(void* const* d_in, const int* in_sizes, int n_in,
                              void* d_out, int out_size, void* d_ws, size_t ws_size,
                              hipStream_t stream)
{
    const float* x    = (const float*)d_in[0];
    const float* kern = (const float*)d_in[1];
    const float* pts  = (const float*)d_in[2];
    float* out = (float*)d_out;

    dim3 block(256, 1, 1);
    dim3 grid(WW / TC, 4, BS);   // 8 x 4 x 16 = 512 blocks, 2/CU (LDS-limited)
    flex_conv_pipe<<<grid, block, 0, stream>>>(x, kern, pts, out);
}

// Round 2
// 114.396 us; speedup vs baseline: 1.0282x; 1.0223x over previous
//
#include <hip/hip_runtime.h>
#include <hip/hip_bf16.h>

// flex_conv via MFMA + async LDS staging (v3).
//
// Math (unchanged, validated R2/R3): t[k=ic*4+d][pixel]: t_d = ctr_d*Xs - PX_d
// (d<3), t_3 = Xs; out[o][pixel] = Kmat[o][k] . t[k][pixel] -> 16x16x32 bf16
// MFMA (A[m=p][k], B[k][n=p], D row=c*4+r col=p).
//
// v3 = v1 geometry (2048 blocks, 31 KB LDS, 5 blocks/CU capacity) + v2's
// async global_load_lds staging.  v1 staged via load->VGPR->ds_write at 72
// VGPRs, which serialized the 8 staging rounds (multiple exposed ~900-cy HBM
// round-trips per block).  v2 fixed that but dropped to 2 blocks/CU (62 KB
// LDS) and convoyed at tile granularity.  Here all ~8 staging DMAs issue
// back-to-back with no VGPR round-trip, the kernel-weight (A fragment) loads
// overlap the DMA, and a single __syncthreads drains.  LDS layout keeps
// row*LC + chunk*4 floats == cid*16 bytes, i.e. the per-wave destination is
// base + lane*16 (global_load_lds requirement).

#define HH 64
#define WW 512
#define HP 62
#define WP 510
#define IC 16
#define OC 32
#define BS 16
#define RB 4            // output rows per block
#define TR (RB + 2)     // staged input rows = 6
#define TC 64           // output cols per block
#define LC 68           // LDS row length in floats (need 66; 68 = 17 float4)
#define NPL 19          // planes staged: 16 x + 3 pts
#define CPR 17          // float4 chunks per row (17*4 = 68)
#define NROWS (NPL * TR)        // 114
#define NCHUNK (NROWS * CPR)    // 1938

typedef __attribute__((ext_vector_type(8))) short short8;
typedef __attribute__((ext_vector_type(4))) float f32x4;

static __device__ __forceinline__ short f2bf(float f) {
    union { __hip_bfloat16 h; short s; } u;
    u.h = __float2bfloat16(f);
    return u.s;
}

__global__ __launch_bounds__(256) void flex_conv_v3(
    const float* __restrict__ x, const float* __restrict__ kern,
    const float* __restrict__ pts, float* __restrict__ out)
{
    __shared__ float lds[NPL * TR * LC];   // 7752 floats = 31008 B

    const int tid = threadIdx.x;
    const int j0 = blockIdx.x * TC;
    int i0 = blockIdx.y * RB;
    if (i0 > HP - RB) i0 = HP - RB;        // tail overlap (benign identical rewrite)
    const int b = blockIdx.z;

    const float* xb = x + (size_t)b * IC * HH * WW;
    const float* pb = pts + (size_t)b * 3 * HH * WW;

    // ---- async cooperative staging: 1938 16B chunks over 256 threads ----
    // LDS byte offset of chunk cid is exactly cid*16 (row stride 68 floats =
    // 17 chunks), so each wave's destinations are base + lane*16: the
    // wave-uniform-base + lane*width pattern global_load_lds requires.
    #pragma unroll
    for (int rnd = 0; rnd < 8; ++rnd) {
        const int cid = tid + rnd * 256;
        if (cid < NCHUNK) {
            const int row = cid / CPR;           // 0..113 = plane*TR + rr
            const int chunk = cid - row * CPR;   // 0..16
            const int plane = row / TR;          // 0..18
            const int rr = row - plane * TR;     // 0..5
            const float* base = (plane < IC)
                ? (xb + (size_t)plane * HH * WW)
                : (pb + (size_t)(plane - IC) * HH * WW);
            int gcol = j0 + chunk * 4;
            if (gcol > WW - 4) gcol = WW - 4;    // clamp (garbage lands in unused cells)
            const float* src = base + (size_t)(i0 + rr) * WW + gcol;
            __builtin_amdgcn_global_load_lds(
                (const __attribute__((address_space(1))) void*)src,
                (__attribute__((address_space(3))) void*)(&lds[row * LC + chunk * 4]),
                16, 0, 0);
        }
    }

    // ---- A fragments: loaded while the DMA above is in flight ----
    const int lane = tid & 63;
    const int wave = tid >> 6;
    const int p = lane & 15;
    const int c = lane >> 4;
    const int tc = wave * 16 + p;        // tile col of this lane's pixel

    short8 a0lo, a0hi, a1lo, a1hi;
    {
        const float4* k0v = (const float4*)(kern + (size_t)p * 64 + c * 8);
        const float4* k1v = (const float4*)(kern + (size_t)(16 + p) * 64 + c * 8);
        float4 v0a = k0v[0], v0b = k0v[1], v0c = k0v[8], v0d = k0v[9];
        float4 v1a = k1v[0], v1b = k1v[1], v1c = k1v[8], v1d = k1v[9];
        a0lo[0]=f2bf(v0a.x); a0lo[1]=f2bf(v0a.y); a0lo[2]=f2bf(v0a.z); a0lo[3]=f2bf(v0a.w);
        a0lo[4]=f2bf(v0b.x); a0lo[5]=f2bf(v0b.y); a0lo[6]=f2bf(v0b.z); a0lo[7]=f2bf(v0b.w);
        a0hi[0]=f2bf(v0c.x); a0hi[1]=f2bf(v0c.y); a0hi[2]=f2bf(v0c.z); a0hi[3]=f2bf(v0c.w);
        a0hi[4]=f2bf(v0d.x); a0hi[5]=f2bf(v0d.y); a0hi[6]=f2bf(v0d.z); a0hi[7]=f2bf(v0d.w);
        a1lo[0]=f2bf(v1a.x); a1lo[1]=f2bf(v1a.y); a1lo[2]=f2bf(v1a.z); a1lo[3]=f2bf(v1a.w);
        a1lo[4]=f2bf(v1b.x); a1lo[5]=f2bf(v1b.y); a1lo[6]=f2bf(v1b.z); a1lo[7]=f2bf(v1b.w);
        a1hi[0]=f2bf(v1c.x); a1hi[1]=f2bf(v1c.y); a1hi[2]=f2bf(v1c.z); a1hi[3]=f2bf(v1c.w);
        a1hi[4]=f2bf(v1d.x); a1hi[5]=f2bf(v1d.y); a1hi[6]=f2bf(v1d.z); a1hi[7]=f2bf(v1d.w);
    }

    __syncthreads();   // drains staging DMA (vmcnt(0)) + barrier

    // ---- window partials from LDS ----
    float xs[4][RB], px0[4][RB], px1[4][RB], px2[4][RB];
    #pragma unroll
    for (int t = 0; t < 4; ++t)
        #pragma unroll
        for (int q = 0; q < RB; ++q) { xs[t][q]=0.f; px0[t][q]=0.f; px1[t][q]=0.f; px2[t][q]=0.f; }
    float c0[RB], c1[RB], c2[RB];

    #pragma unroll
    for (int rr = 0; rr < TR; ++rr) {
        const float* lp0 = &lds[(IC * TR + rr) * LC + tc];        // pts plane 0
        const float* lp1 = &lds[((IC + 1) * TR + rr) * LC + tc];
        const float* lp2 = &lds[((IC + 2) * TR + rr) * LC + tc];
        const float pa0 = lp0[0], pm0 = lp0[1], pz0 = lp0[2];
        const float pa1 = lp1[0], pm1 = lp1[1], pz1 = lp1[2];
        const float pa2 = lp2[0], pm2 = lp2[1], pz2 = lp2[2];
        if (rr >= 1 && rr <= RB) { c0[rr-1] = pm0; c1[rr-1] = pm1; c2[rr-1] = pm2; }
        #pragma unroll
        for (int t = 0; t < 4; ++t) {
            const int ic = (t >> 1) * 8 + 2 * c + (t & 1);
            const float* lx = &lds[(ic * TR + rr) * LC + tc];
            const float x0 = lx[0], x1 = lx[1], x2 = lx[2];
            const float rsx = x0 + x1 + x2;
            float r0 = pa0 * x0; r0 = fmaf(pm0, x1, r0); r0 = fmaf(pz0, x2, r0);
            float r1 = pa1 * x0; r1 = fmaf(pm1, x1, r1); r1 = fmaf(pz1, x2, r1);
            float r2 = pa2 * x0; r2 = fmaf(pm2, x1, r2); r2 = fmaf(pz2, x2, r2);
            #pragma unroll
            for (int q = 0; q < RB; ++q) {
                if (rr >= q && rr <= q + 2) {
                    xs[t][q] += rsx; px0[t][q] += r0; px1[t][q] += r1; px2[t][q] += r2;
                }
            }
        }
    }

    // ---- per output row: B fragments -> MFMA -> store ----
    const int j = j0 + tc;
    #pragma unroll
    for (int q = 0; q < RB; ++q) {
        short8 blo, bhi;
        #pragma unroll
        for (int t = 0; t < 4; ++t) {
            const short t0 = f2bf(fmaf(c0[q], xs[t][q], -px0[t][q]));
            const short t1 = f2bf(fmaf(c1[q], xs[t][q], -px1[t][q]));
            const short t2 = f2bf(fmaf(c2[q], xs[t][q], -px2[t][q]));
            const short t3 = f2bf(xs[t][q]);
            const int s = (t & 1) * 4;
            if (t < 2) { blo[s+0]=t0; blo[s+1]=t1; blo[s+2]=t2; blo[s+3]=t3; }
            else       { bhi[s+0]=t0; bhi[s+1]=t1; bhi[s+2]=t2; bhi[s+3]=t3; }
        }
        f32x4 acc0 = {0.f,0.f,0.f,0.f}, acc1 = {0.f,0.f,0.f,0.f};
        acc0 = __builtin_amdgcn_mfma_f32_16x16x32_bf16(a0lo, blo, acc0, 0, 0, 0);
        acc0 = __builtin_amdgcn_mfma_f32_16x16x32_bf16(a0hi, bhi, acc0, 0, 0, 0);
        acc1 = __builtin_amdgcn_mfma_f32_16x16x32_bf16(a1lo, blo, acc1, 0, 0, 0);
        acc1 = __builtin_amdgcn_mfma_f32_16x16x32_bf16(a1hi, bhi, acc1, 0, 0, 0);
        if (j < WP) {
            float* ob = out + (size_t)b * OC * HP * WP + (size_t)(i0 + q) * WP + j;
            #pragma unroll
            for (int r = 0; r < 4; ++r) {
                const int o = c * 4 + r;
                ob[(size_t)o * HP * WP]        = acc0[r];
                ob[(size_t)(o + 16) * HP * WP] = acc1[r];
            }
        }
    }
}

extern "C" void kernel_launch(void* const* d_in, const int* in_sizes, int n_in,
                              void* d_out, int out_size, void* d_ws, size_t ws_size,
                              hipStream_t stream)
{
    const float* x    = (const float*)d_in[0];
    const float* kern = (const float*)d_in[1];
    const float* pts  = (const float*)d_in[2];
    float* out = (float*)d_out;

    dim3 block(256, 1, 1);
    dim3 grid(WW / TC, (HP + RB - 1) / RB, BS);   // 8 x 16 x 16 = 2048 blocks
    flex_conv_v3<<<grid, block, 0, stream>>>(x, kern, pts, out);
}